// Round 1
// baseline (258.423 us; speedup 1.0000x reference)
//
#include <hip/hip_runtime.h>
#include <stdint.h>

#define BS 2048   // B*S
#define E_ 512
#define NH 8
#define HD 64
#define TMAX 20

// ---------------------------------------------------------------------------
// f32 tiled GEMM: C[M,N] = A[M,K] @ W[K,N] (+bias). BM=128 BN=64 BK=16,
// 256 threads, 8x4 micro-tile. All dims divide exactly for this problem.
// ---------------------------------------------------------------------------
__device__ __forceinline__ void gemm_body(const float* __restrict__ A,
    const float* __restrict__ W, const float* __restrict__ bias,
    float* __restrict__ C, int M, int N, int K)
{
    __shared__ __align__(16) float As[16][132];   // transposed A tile, padded
    __shared__ __align__(16) float Bs[16][64];
    int tid = threadIdx.x;
    int m0 = blockIdx.y * 128;
    int n0 = blockIdx.x * 64;
    int ty = tid >> 4, tx = tid & 15;
    float acc[8][4];
#pragma unroll
    for (int r = 0; r < 8; ++r)
#pragma unroll
        for (int c = 0; c < 4; ++c) acc[r][c] = 0.f;

    int arow = tid >> 2;       // 0..63
    int acol4 = tid & 3;       // 0..3
    int brow = tid >> 4;       // 0..15
    int bcol4 = tid & 15;

    for (int k0 = 0; k0 < K; k0 += 16) {
#pragma unroll
        for (int rr = 0; rr < 2; ++rr) {
            int r = arow + rr * 64;
            float4 va = *(const float4*)(&A[(size_t)(m0 + r) * K + k0 + acol4 * 4]);
            As[acol4 * 4 + 0][r] = va.x;
            As[acol4 * 4 + 1][r] = va.y;
            As[acol4 * 4 + 2][r] = va.z;
            As[acol4 * 4 + 3][r] = va.w;
        }
        float4 vb = *(const float4*)(&W[(size_t)(k0 + brow) * N + n0 + bcol4 * 4]);
        *(float4*)(&Bs[brow][bcol4 * 4]) = vb;
        __syncthreads();
#pragma unroll
        for (int kk = 0; kk < 16; ++kk) {
            float4 a0 = *(const float4*)(&As[kk][ty * 8]);
            float4 a1 = *(const float4*)(&As[kk][ty * 8 + 4]);
            float4 b4 = *(const float4*)(&Bs[kk][tx * 4]);
            float ar[8] = {a0.x, a0.y, a0.z, a0.w, a1.x, a1.y, a1.z, a1.w};
            float br[4] = {b4.x, b4.y, b4.z, b4.w};
#pragma unroll
            for (int r = 0; r < 8; ++r)
#pragma unroll
                for (int c = 0; c < 4; ++c)
                    acc[r][c] = fmaf(ar[r], br[c], acc[r][c]);
        }
        __syncthreads();
    }
#pragma unroll
    for (int r = 0; r < 8; ++r) {
        int row = m0 + ty * 8 + r;
        float4 o;
        o.x = acc[r][0]; o.y = acc[r][1]; o.z = acc[r][2]; o.w = acc[r][3];
        if (bias) {
            o.x += bias[n0 + tx * 4 + 0];
            o.y += bias[n0 + tx * 4 + 1];
            o.z += bias[n0 + tx * 4 + 2];
            o.w += bias[n0 + tx * 4 + 3];
        }
        *(float4*)(&C[(size_t)row * N + n0 + tx * 4]) = o;
    }
}

__global__ __launch_bounds__(256) void gemm_qkv_kernel(const float* __restrict__ x,
    const float* __restrict__ Wq, const float* __restrict__ Wk, const float* __restrict__ Wv,
    float* __restrict__ q, float* __restrict__ k, float* __restrict__ v)
{
    int z = blockIdx.z;
    const float* W = (z == 0) ? Wq : (z == 1) ? Wk : Wv;
    float* C = (z == 0) ? q : (z == 1) ? k : v;
    gemm_body(x, W, nullptr, C, BS, E_, E_);
}

__global__ __launch_bounds__(256) void gemm_out_kernel(const float* __restrict__ ctx,
    const float* __restrict__ Wo, const float* __restrict__ bo, float* __restrict__ out)
{
    gemm_body(ctx, Wo, bo, out, BS, E_, E_);
}

// ---------------------------------------------------------------------------
// Gate/complexity MLPs -> T_i. 16 tokens per 256-thread block.
// ---------------------------------------------------------------------------
__global__ __launch_bounds__(256) void mlp_gate_kernel(const float* __restrict__ x,
    const float* __restrict__ g1, const float* __restrict__ gb1,
    const float* __restrict__ g2, const float* __restrict__ gb2,
    const float* __restrict__ g3, const float* __restrict__ gb3,
    const float* __restrict__ c1, const float* __restrict__ cb1,
    const float* __restrict__ c2, const float* __restrict__ cb2,
    int* __restrict__ Ti)
{
    __shared__ __align__(16) float xsh[16][512];
    __shared__ float h1sh[16][64];
    __shared__ float h2sh[16][32];
    __shared__ float gsh[16];
    int tid = threadIdx.x;
    int tok0 = blockIdx.x * 16;

    const float4* xg = (const float4*)(&x[(size_t)tok0 * 512]);
    float4* xs4 = (float4*)(&xsh[0][0]);
    for (int i = tid; i < 16 * 128; i += 256) xs4[i] = xg[i];
    __syncthreads();

    {   // h1 = relu(x@g1+gb1): lane l = output ch, wave handles 4 tokens
        int l = tid & 63, tg = tid >> 6;
        float a0 = gb1[l], a1 = a0, a2 = a0, a3 = a0;
#pragma unroll 8
        for (int e = 0; e < 512; ++e) {
            float w = g1[e * 64 + l];
            a0 = fmaf(xsh[tg][e], w, a0);
            a1 = fmaf(xsh[tg + 4][e], w, a1);
            a2 = fmaf(xsh[tg + 8][e], w, a2);
            a3 = fmaf(xsh[tg + 12][e], w, a3);
        }
        h1sh[tg][l] = fmaxf(a0, 0.f);
        h1sh[tg + 4][l] = fmaxf(a1, 0.f);
        h1sh[tg + 8][l] = fmaxf(a2, 0.f);
        h1sh[tg + 12][l] = fmaxf(a3, 0.f);
    }
    __syncthreads();
    {   // h2 = relu(h1@g2+gb2)
        int m = tid & 31, tg = tid >> 5;
#pragma unroll
        for (int tt = 0; tt < 2; ++tt) {
            int tok = tg + tt * 8;
            float a = gb2[m];
#pragma unroll 8
            for (int l = 0; l < 64; ++l) a = fmaf(h1sh[tok][l], g2[l * 32 + m], a);
            h2sh[tok][m] = fmaxf(a, 0.f);
        }
    }
    __syncthreads();
    if (tid < 16) {
        float a = gb3[0];
#pragma unroll 8
        for (int m = 0; m < 32; ++m) a = fmaf(h2sh[tid][m], g3[m], a);
        gsh[tid] = 1.f / (1.f + expf(-a));
    }
    __syncthreads();
    {   // comp hidden = relu(x@c1+cb1)  (reuse h2sh)
        int m = tid & 31, tg = tid >> 5;
#pragma unroll
        for (int tt = 0; tt < 2; ++tt) {
            int tok = tg + tt * 8;
            float a = cb1[m];
#pragma unroll 8
            for (int e = 0; e < 512; ++e) a = fmaf(xsh[tok][e], c1[e * 32 + m], a);
            h2sh[tok][m] = fmaxf(a, 0.f);
        }
    }
    __syncthreads();
    if (tid < 16) {
        float a = cb2[0];
#pragma unroll 8
        for (int m = 0; m < 32; ++m) a = fmaf(h2sh[tid][m], c2[m], a);
        float comp = 1.f / (1.f + expf(-a));
        float comb = 0.7f * gsh[tid] + 0.3f * comp;
        int t = (int)ceilf(comb * 20.f);
        t = t < 1 ? 1 : (t > 20 ? 20 : t);
        Ti[tok0 + tid] = t;
    }
}

// ---------------------------------------------------------------------------
// LIF + window mask. One wave per (token, head). lane = channel within head.
// mode 0/1 (q/k): bit-pack masked spikes via ballot -> pack[(b*8+h)*512+i][t]
// mode 2   (v)  : per-channel masked spike count -> vmean[(b*8+h)*512+i][d]
// ---------------------------------------------------------------------------
__global__ __launch_bounds__(256) void lif_kernel(const float* __restrict__ q,
    const float* __restrict__ k, const float* __restrict__ v,
    const int* __restrict__ Ti,
    const float* __restrict__ alphap, const float* __restrict__ betap,
    unsigned long long* __restrict__ qpack, unsigned long long* __restrict__ kpack,
    float* __restrict__ vmean)
{
    int mode = blockIdx.y;
    const float* src = (mode == 0) ? q : (mode == 1) ? k : v;
    int w = blockIdx.x * 4 + (threadIdx.x >> 6);   // 0..16383
    int lane = threadIdx.x & 63;
    int token = w >> 3;
    int h = w & 7;
    float xin = src[(size_t)token * 512 + h * 64 + lane];
    int T = Ti[token];
    float alpha = alphap[0], beta = betap[0];
    float vm = 0.f, isyn = 0.f;
    unsigned long long myword = 0ull;
    int cnt = 0;
#pragma unroll
    for (int t = 0; t < TMAX; ++t) {
        isyn = alpha * isyn + xin;
        vm = beta * vm + isyn;
        bool sp = vm >= 1.0f;
        if (sp) vm = 0.f;
        bool msk = sp && (t < T);
        if (mode < 2) {
            unsigned long long word = __ballot(msk ? 1 : 0);
            if (lane == t) myword = word;
        } else {
            cnt += msk ? 1 : 0;
        }
    }
    int b = token >> 9, i = token & 511;
    size_t prow = (size_t)(b * 8 + h) * 512 + i;
    if (mode == 0) { if (lane < TMAX) qpack[prow * TMAX + lane] = myword; }
    else if (mode == 1) { if (lane < TMAX) kpack[prow * TMAX + lane] = myword; }
    else { vmean[prow * 64 + lane] = (float)cnt * 0.05f; }
}

// ---------------------------------------------------------------------------
// scores (popcount) + softmax + PV fused. One block = (b,h, 16 query rows).
// ---------------------------------------------------------------------------
__global__ __launch_bounds__(256) void attn_kernel(
    const unsigned long long* __restrict__ qpack,
    const unsigned long long* __restrict__ kpack,
    const float* __restrict__ vmean,
    float* __restrict__ ctx)
{
    __shared__ unsigned long long qw[16][21];
    __shared__ float s_lds[16][513];
    __shared__ float inv_lds[16];
    __shared__ __align__(16) char stg_raw[32768];   // klds[128][21] (21.5KB) | vlds[128][64] (32KB)
    unsigned long long (*klds)[21] = (unsigned long long (*)[21])stg_raw;
    float (*vlds)[64] = (float (*)[64])stg_raw;

    int tid = threadIdx.x;
    int bh = blockIdx.x >> 5;
    int i0 = (blockIdx.x & 31) << 4;

    size_t qbase = ((size_t)bh * 512 + i0) * TMAX;
    for (int idx = tid; idx < 16 * TMAX; idx += 256)
        qw[idx / TMAX][idx % TMAX] = qpack[qbase + idx];
    __syncthreads();

    int irow = tid >> 4, jc = tid & 15;
    unsigned long long qr[TMAX];
#pragma unroll
    for (int t = 0; t < TMAX; ++t) qr[t] = qw[irow][t];

    size_t kbase = (size_t)bh * 512 * TMAX;
    for (int jt = 0; jt < 4; ++jt) {
        __syncthreads();
        for (int idx = tid; idx < 128 * TMAX; idx += 256)
            klds[idx / TMAX][idx % TMAX] = kpack[kbase + (size_t)jt * 128 * TMAX + idx];
        __syncthreads();
#pragma unroll
        for (int jj = 0; jj < 8; ++jj) {
            int j = jc + jj * 16;
            int acc = 0;
#pragma unroll
            for (int t = 0; t < TMAX; ++t)
                acc += __popcll(qr[t] & klds[j][t]);
            s_lds[irow][jt * 128 + j] = 0.125f * (float)acc;
        }
    }
    __syncthreads();

    // softmax over j (16 threads per row; stride-16 scan avoids bank conflicts)
    float m = -1e30f;
    for (int s = 0; s < 32; ++s) m = fmaxf(m, s_lds[irow][jc + s * 16]);
#pragma unroll
    for (int o = 1; o < 16; o <<= 1) m = fmaxf(m, __shfl_xor(m, o));
    float lsum = 0.f;
    for (int s = 0; s < 32; ++s) {
        int j = jc + s * 16;
        float p = expf(s_lds[irow][j] - m);
        s_lds[irow][j] = p;
        lsum += p;
    }
#pragma unroll
    for (int o = 1; o < 16; o <<= 1) lsum += __shfl_xor(lsum, o);
    if (jc == 0) inv_lds[irow] = 1.f / lsum;

    // PV: thread (i2, dc) accumulates ctx[i2][dc*4..dc*4+3]
    int i2 = tid >> 4, dc = tid & 15;
    float4 acc4 = {0.f, 0.f, 0.f, 0.f};
    size_t vbase = (size_t)bh * 512 * 64;
    for (int jt = 0; jt < 4; ++jt) {
        __syncthreads();
        {
            const float4* vsrc = (const float4*)(&vmean[vbase + (size_t)jt * 128 * 64]);
            float4* vdst = (float4*)stg_raw;
            for (int idx = tid; idx < 2048; idx += 256) vdst[idx] = vsrc[idx];
        }
        __syncthreads();
#pragma unroll 4
        for (int j = 0; j < 128; ++j) {
            float p = s_lds[i2][jt * 128 + j];
            float4 vv = *(const float4*)(&vlds[j][dc * 4]);
            acc4.x = fmaf(p, vv.x, acc4.x);
            acc4.y = fmaf(p, vv.y, acc4.y);
            acc4.z = fmaf(p, vv.z, acc4.z);
            acc4.w = fmaf(p, vv.w, acc4.w);
        }
    }
    float inv = inv_lds[i2];
    acc4.x *= inv; acc4.y *= inv; acc4.z *= inv; acc4.w *= inv;
    int b = bh >> 3, h = bh & 7;
    int row = b * 512 + i0 + i2;
    *(float4*)(&ctx[(size_t)row * 512 + h * 64 + dc * 4]) = acc4;
}

// ---------------------------------------------------------------------------
extern "C" void kernel_launch(void* const* d_in, const int* in_sizes, int n_in,
                              void* d_out, int out_size, void* d_ws, size_t ws_size,
                              hipStream_t stream) {
    const float* x   = (const float*)d_in[0];
    const float* Wq  = (const float*)d_in[1];
    const float* Wk  = (const float*)d_in[2];
    const float* Wv  = (const float*)d_in[3];
    const float* Wo  = (const float*)d_in[4];
    const float* bo  = (const float*)d_in[5];
    const float* g1  = (const float*)d_in[6];
    const float* gb1 = (const float*)d_in[7];
    const float* g2  = (const float*)d_in[8];
    const float* gb2 = (const float*)d_in[9];
    const float* g3  = (const float*)d_in[10];
    const float* gb3 = (const float*)d_in[11];
    const float* c1  = (const float*)d_in[12];
    const float* cb1 = (const float*)d_in[13];
    const float* c2  = (const float*)d_in[14];
    const float* cb2 = (const float*)d_in[15];
    const float* alpha = (const float*)d_in[16];
    const float* beta  = (const float*)d_in[17];
    float* out = (float*)d_out;

    char* w = (char*)d_ws;
    float* q    = (float*)w;                         w += (size_t)BS * E_ * 4;
    float* kbuf = (float*)w;                         w += (size_t)BS * E_ * 4;
    float* vbuf = (float*)w;                         w += (size_t)BS * E_ * 4;
    int* Ti     = (int*)w;                           w += (size_t)BS * 4;
    unsigned long long* qpack = (unsigned long long*)w; w += (size_t)BS * NH * TMAX * 8;
    unsigned long long* kpack = (unsigned long long*)w; w += (size_t)BS * NH * TMAX * 8;
    float* vmean = (float*)w;                        w += (size_t)BS * E_ * 4;
    float* ctx = q;   // safe alias: q fully consumed by lif_kernel before attn

    gemm_qkv_kernel<<<dim3(8, 16, 3), 256, 0, stream>>>(x, Wq, Wk, Wv, q, kbuf, vbuf);
    mlp_gate_kernel<<<128, 256, 0, stream>>>(x, g1, gb1, g2, gb2, g3, gb3,
                                             c1, cb1, c2, cb2, Ti);
    lif_kernel<<<dim3(4096, 3), 256, 0, stream>>>(q, kbuf, vbuf, Ti, alpha, beta,
                                                  qpack, kpack, vmean);
    attn_kernel<<<1024, 256, 0, stream>>>(qpack, kpack, vmean, ctx);
    gemm_out_kernel<<<dim3(8, 16), 256, 0, stream>>>(ctx, Wo, bo, out);
}